// Round 4
// baseline (522.942 us; speedup 1.0000x reference)
//
#include <hip/hip_runtime.h>

namespace {

constexpr int B = 2;
constexpr int N = 200000;
constexpr int C = 16;
constexpr int D = 256;
constexpr int H = 256;
constexpr int W = 32;
constexpr int V = D * H * W;    // 2^21 voxels per batch
constexpr int BV = B * V;       // 4,194,304
constexpr unsigned NIL = 0xFFFFFFFFu;

// Native clang vector types — required for __builtin_nontemporal_{load,store}
// (HIP_vector_type structs are rejected). Layout-compatible with float4/uint4.
typedef float  vf4 __attribute__((ext_vector_type(4)));
typedef unsigned vu4 __attribute__((ext_vector_type(4)));

// Replicate reference op order exactly: (p - lo) / (hi - lo) * dim, trunc, clip.
// (This exact formulation gave absmax 0 in rounds 1-2 — do not change.)
__device__ __forceinline__ int voxel_of(float x, float y, float z) {
    float fx = (x - (-48.0f)) / 96.0f * 256.0f;
    float fy = (y - (-48.0f)) / 96.0f * 256.0f;
    float fz = (z - (-4.0f)) / 5.5f * 32.0f;
    int vx = (int)fx;
    int vy = (int)fy;
    int vz = (int)fz;
    vx = vx < 0 ? 0 : (vx > D - 1 ? D - 1 : vx);
    vy = vy < 0 ? 0 : (vy > H - 1 ? H - 1 : vy);
    vz = vz < 0 ? 0 : (vz > W - 1 ? W - 1 : vz);
    return (vx * H + vy) * W + vz;
}

__global__ __launch_bounds__(256) void init_head(vu4* __restrict__ head4, int n4) {
    int i = blockIdx.x * blockDim.x + threadIdx.x;
    if (i < n4) {
        vu4 nil4 = {NIL, NIL, NIL, NIL};
        __builtin_nontemporal_store(nil4, head4 + i);
    }
}

// One atomicExch per point: push point idx onto its voxel's intrusive list.
__global__ __launch_bounds__(256) void build_list(
    const float* __restrict__ pts, unsigned* __restrict__ head,
    unsigned* __restrict__ nxt) {
    int idx = blockIdx.x * blockDim.x + threadIdx.x;
    if (idx >= B * N) return;
    const float* p = pts + (size_t)idx * 3;
    float x = __builtin_nontemporal_load(p + 0);
    float y = __builtin_nontemporal_load(p + 1);
    float z = __builtin_nontemporal_load(p + 2);
    int v = voxel_of(x, y, z);
    int b = idx / N;
    unsigned old = atomicExch(head + (size_t)b * V + v, (unsigned)idx);
    __builtin_nontemporal_store(old, nxt + idx);
}

// One thread per 4 consecutive voxels. Fast path for all-empty (~68% of
// threads). Occupied voxels issue their first-element feature + nxt loads
// up front (MLP); the rare (~5% of occupied) count>=2 tail loops after.
__global__ __launch_bounds__(256) void finalize(
    const vu4* __restrict__ head4, const unsigned* __restrict__ nxt,
    const vf4* __restrict__ fts4, float* __restrict__ out) {
    int g = blockIdx.x * blockDim.x + threadIdx.x;
    if (g >= BV / 4) return;
    vu4 h4 = __builtin_nontemporal_load(head4 + g);
    int t0 = g * 4;               // first (b,v) flat index of this group
    int b = t0 >> 21;             // V = 2^21
    int v = t0 & (V - 1);
    float* obase = out + (size_t)b * C * V + v;

    // AND == all-ones iff every head is NIL.
    if ((h4.x & h4.y & h4.z & h4.w) == NIL) {
        vf4 z = {0.f, 0.f, 0.f, 0.f};
#pragma unroll
        for (int c = 0; c < 16; ++c)
            __builtin_nontemporal_store(z, (vf4*)(obase + (size_t)c * V));
        return;
    }

    unsigned hs[4] = {h4.x, h4.y, h4.z, h4.w};
    float s[4][16];
    float cnt[4];
    unsigned nx[4];

#pragma unroll
    for (int j = 0; j < 4; ++j) {
        cnt[j] = 0.f;
#pragma unroll
        for (int c = 0; c < 16; ++c) s[j][c] = 0.f;
        nx[j] = NIL;
        if (hs[j] != NIL) {
            const vf4* fp = fts4 + (size_t)hs[j] * 4;
            vf4 f0 = __builtin_nontemporal_load(fp + 0);
            vf4 f1 = __builtin_nontemporal_load(fp + 1);
            vf4 f2 = __builtin_nontemporal_load(fp + 2);
            vf4 f3 = __builtin_nontemporal_load(fp + 3);
            nx[j] = __builtin_nontemporal_load(nxt + hs[j]);
            s[j][0]  = f0.x; s[j][1]  = f0.y; s[j][2]  = f0.z; s[j][3]  = f0.w;
            s[j][4]  = f1.x; s[j][5]  = f1.y; s[j][6]  = f1.z; s[j][7]  = f1.w;
            s[j][8]  = f2.x; s[j][9]  = f2.y; s[j][10] = f2.z; s[j][11] = f2.w;
            s[j][12] = f3.x; s[j][13] = f3.y; s[j][14] = f3.z; s[j][15] = f3.w;
            cnt[j] = 1.f;
        }
    }

    // Rare tail: voxels with >= 2 points.
    while (nx[0] != NIL || nx[1] != NIL || nx[2] != NIL || nx[3] != NIL) {
#pragma unroll
        for (int j = 0; j < 4; ++j) {
            unsigned h = nx[j];
            if (h != NIL) {
                const vf4* fp = fts4 + (size_t)h * 4;
                vf4 f0 = __builtin_nontemporal_load(fp + 0);
                vf4 f1 = __builtin_nontemporal_load(fp + 1);
                vf4 f2 = __builtin_nontemporal_load(fp + 2);
                vf4 f3 = __builtin_nontemporal_load(fp + 3);
                nx[j] = __builtin_nontemporal_load(nxt + h);
                s[j][0]  += f0.x; s[j][1]  += f0.y; s[j][2]  += f0.z; s[j][3]  += f0.w;
                s[j][4]  += f1.x; s[j][5]  += f1.y; s[j][6]  += f1.z; s[j][7]  += f1.w;
                s[j][8]  += f2.x; s[j][9]  += f2.y; s[j][10] += f2.z; s[j][11] += f2.w;
                s[j][12] += f3.x; s[j][13] += f3.y; s[j][14] += f3.z; s[j][15] += f3.w;
                cnt[j] += 1.f;
            }
        }
    }

#pragma unroll
    for (int j = 0; j < 4; ++j) {
        if (cnt[j] > 1.f) {   // cnt==1: s/1 is exact, skip IEEE div
            float c = cnt[j];
#pragma unroll
            for (int k = 0; k < 16; ++k) s[j][k] /= c;
        }
    }

#pragma unroll
    for (int c = 0; c < 16; ++c) {
        vf4 o = {s[0][c], s[1][c], s[2][c], s[3][c]};
        __builtin_nontemporal_store(o, (vf4*)(obase + (size_t)c * V));
    }
}

// ---- Fallback (tiny-workspace safety net): direct strided atomics into out.
__global__ __launch_bounds__(256) void zero_f4(float4* __restrict__ p, int n4) {
    int i = blockIdx.x * blockDim.x + threadIdx.x;
    if (i < n4) p[i] = make_float4(0.f, 0.f, 0.f, 0.f);
}

__global__ __launch_bounds__(256) void count_only(
    const float* __restrict__ pts, float* __restrict__ counts) {
    int idx = blockIdx.x * blockDim.x + threadIdx.x;
    if (idx >= B * N) return;
    int b = idx / N;
    const float* p = pts + (size_t)idx * 3;
    int v = voxel_of(p[0], p[1], p[2]);
    atomicAdd(counts + (size_t)b * V + v, 1.0f);
}

__global__ __launch_bounds__(256) void scatter_direct(
    const float* __restrict__ pts, const float* __restrict__ fts,
    const float* __restrict__ counts, float* __restrict__ out) {
    int idx = blockIdx.x * blockDim.x + threadIdx.x;
    if (idx >= B * N) return;
    int b = idx / N;
    const float* p = pts + (size_t)idx * 3;
    int v = voxel_of(p[0], p[1], p[2]);
    float cnt = counts[(size_t)b * V + v];
    const float* f = fts + (size_t)idx * C;
    float* o = out + (size_t)b * C * V + v;
#pragma unroll
    for (int c = 0; c < 16; ++c) atomicAdd(o + (size_t)c * V, f[c] / cnt);
}

}  // namespace

extern "C" void kernel_launch(void* const* d_in, const int* in_sizes, int n_in,
                              void* d_out, int out_size, void* d_ws, size_t ws_size,
                              hipStream_t stream) {
    const float* pts = (const float*)d_in[0];   // [B, N, 3]
    const float* fts = (const float*)d_in[1];   // [B, N, C]
    float* out = (float*)d_out;                 // [B, C, D, H, W]

    const int n_pts = B * N;                    // 400,000
    const int pt_blocks = (n_pts + 255) / 256;

    const size_t head_bytes = (size_t)BV * sizeof(unsigned);      // 16.8 MB
    const size_t nxt_bytes = (size_t)n_pts * sizeof(unsigned);    // 1.6 MB

    if (ws_size >= head_bytes + nxt_bytes) {
        unsigned* head = (unsigned*)d_ws;
        unsigned* nxt = head + (size_t)BV;

        int head_n4 = BV / 4;  // 1,048,576
        init_head<<<(head_n4 + 255) / 256, 256, 0, stream>>>((vu4*)head, head_n4);
        build_list<<<pt_blocks, 256, 0, stream>>>(pts, head, nxt);

        int fin_threads = BV / 4;  // 1,048,576 (one per 4 voxels)
        finalize<<<(fin_threads + 255) / 256, 256, 0, stream>>>(
            (const vu4*)head, nxt, (const vf4*)fts, out);
    } else {
        // Safety net: direct atomic accumulation into out.
        float* counts = (float*)d_ws;
        int counts_f4 = BV / 4;
        zero_f4<<<(counts_f4 + 255) / 256, 256, 0, stream>>>((float4*)counts, counts_f4);
        int out_f4 = out_size / 4;
        zero_f4<<<(out_f4 + 255) / 256, 256, 0, stream>>>((float4*)out, out_f4);
        count_only<<<pt_blocks, 256, 0, stream>>>(pts, counts);
        scatter_direct<<<pt_blocks, 256, 0, stream>>>(pts, fts, counts, out);
    }
}

// Round 5
// 327.522 us; speedup vs baseline: 1.5967x; 1.5967x over previous
//
#include <hip/hip_runtime.h>

namespace {

constexpr int B = 2;
constexpr int N = 200000;
constexpr int C = 16;
constexpr int D = 256;
constexpr int H = 256;
constexpr int W = 32;
constexpr int V = D * H * W;    // 2^21 voxels per batch
constexpr int BV = B * V;       // 4,194,304
constexpr unsigned NIL = 0xFFFFFFFFu;

// Replicate reference op order exactly: (p - lo) / (hi - lo) * dim, trunc, clip.
// (This exact formulation gave absmax 0 in rounds 1-4 — do not change.)
__device__ __forceinline__ int voxel_of(float x, float y, float z) {
    float fx = (x - (-48.0f)) / 96.0f * 256.0f;
    float fy = (y - (-48.0f)) / 96.0f * 256.0f;
    float fz = (z - (-4.0f)) / 5.5f * 32.0f;
    int vx = (int)fx;
    int vy = (int)fy;
    int vz = (int)fz;
    vx = vx < 0 ? 0 : (vx > D - 1 ? D - 1 : vx);
    vy = vy < 0 ? 0 : (vy > H - 1 ? H - 1 : vy);
    vz = vz < 0 ? 0 : (vz > W - 1 ? W - 1 : vz);
    return (vx * H + vy) * W + vz;
}

// NOTE (R4 lesson): no __builtin_nontemporal_* anywhere. NT loads killed the
// L2 hits on head/nxt (290 µs vs 85 µs cached), NT stores amplified WRITE_SIZE.

__global__ __launch_bounds__(256) void init_head(uint4* __restrict__ head4, int n4) {
    int i = blockIdx.x * blockDim.x + threadIdx.x;
    if (i < n4) head4[i] = make_uint4(NIL, NIL, NIL, NIL);
}

// One atomicExch per point: push point idx onto its voxel's intrusive list.
__global__ __launch_bounds__(256) void build_list(
    const float* __restrict__ pts, unsigned* __restrict__ head,
    unsigned* __restrict__ nxt) {
    int idx = blockIdx.x * blockDim.x + threadIdx.x;
    if (idx >= B * N) return;
    const float* p = pts + (size_t)idx * 3;
    int v = voxel_of(p[0], p[1], p[2]);
    int b = idx / N;
    unsigned old = atomicExch(head + (size_t)b * V + v, (unsigned)idx);
    nxt[idx] = old;
}

// One thread per 4 consecutive voxels. Fast path for all-empty (~68% of
// threads). Occupied voxels issue their first-element feature + nxt loads
// up front (MLP); the rare (~5% of occupied) count>=2 tail loops after.
__global__ __launch_bounds__(256) void finalize(
    const uint4* __restrict__ head4, const unsigned* __restrict__ nxt,
    const float4* __restrict__ fts4, float* __restrict__ out) {
    int g = blockIdx.x * blockDim.x + threadIdx.x;
    if (g >= BV / 4) return;
    uint4 h4 = head4[g];
    int t0 = g * 4;               // first (b,v) flat index of this group
    int b = t0 >> 21;             // V = 2^21
    int v = t0 & (V - 1);
    float* obase = out + (size_t)b * C * V + v;

    // AND == all-ones iff every head is NIL.
    if ((h4.x & h4.y & h4.z & h4.w) == NIL) {
        float4 z = make_float4(0.f, 0.f, 0.f, 0.f);
#pragma unroll
        for (int c = 0; c < 16; ++c)
            *(float4*)(obase + (size_t)c * V) = z;
        return;
    }

    unsigned hs[4] = {h4.x, h4.y, h4.z, h4.w};
    float s[4][16];
    float cnt[4];
    unsigned nx[4];

#pragma unroll
    for (int j = 0; j < 4; ++j) {
        cnt[j] = 0.f;
#pragma unroll
        for (int c = 0; c < 16; ++c) s[j][c] = 0.f;
        nx[j] = NIL;
        if (hs[j] != NIL) {
            const float4* fp = fts4 + (size_t)hs[j] * 4;
            float4 f0 = fp[0];
            float4 f1 = fp[1];
            float4 f2 = fp[2];
            float4 f3 = fp[3];
            nx[j] = nxt[hs[j]];
            s[j][0]  = f0.x; s[j][1]  = f0.y; s[j][2]  = f0.z; s[j][3]  = f0.w;
            s[j][4]  = f1.x; s[j][5]  = f1.y; s[j][6]  = f1.z; s[j][7]  = f1.w;
            s[j][8]  = f2.x; s[j][9]  = f2.y; s[j][10] = f2.z; s[j][11] = f2.w;
            s[j][12] = f3.x; s[j][13] = f3.y; s[j][14] = f3.z; s[j][15] = f3.w;
            cnt[j] = 1.f;
        }
    }

    // Rare tail: voxels with >= 2 points.
    while (nx[0] != NIL || nx[1] != NIL || nx[2] != NIL || nx[3] != NIL) {
#pragma unroll
        for (int j = 0; j < 4; ++j) {
            unsigned h = nx[j];
            if (h != NIL) {
                const float4* fp = fts4 + (size_t)h * 4;
                float4 f0 = fp[0];
                float4 f1 = fp[1];
                float4 f2 = fp[2];
                float4 f3 = fp[3];
                nx[j] = nxt[h];
                s[j][0]  += f0.x; s[j][1]  += f0.y; s[j][2]  += f0.z; s[j][3]  += f0.w;
                s[j][4]  += f1.x; s[j][5]  += f1.y; s[j][6]  += f1.z; s[j][7]  += f1.w;
                s[j][8]  += f2.x; s[j][9]  += f2.y; s[j][10] += f2.z; s[j][11] += f2.w;
                s[j][12] += f3.x; s[j][13] += f3.y; s[j][14] += f3.z; s[j][15] += f3.w;
                cnt[j] += 1.f;
            }
        }
    }

#pragma unroll
    for (int j = 0; j < 4; ++j) {
        if (cnt[j] > 1.f) {   // cnt==1: s/1 is exact, skip IEEE div
            float c = cnt[j];
#pragma unroll
            for (int k = 0; k < 16; ++k) s[j][k] /= c;
        }
    }

#pragma unroll
    for (int c = 0; c < 16; ++c) {
        float4 o = make_float4(s[0][c], s[1][c], s[2][c], s[3][c]);
        *(float4*)(obase + (size_t)c * V) = o;
    }
}

// ---- Fallback (tiny-workspace safety net): direct strided atomics into out.
__global__ __launch_bounds__(256) void zero_f4(float4* __restrict__ p, int n4) {
    int i = blockIdx.x * blockDim.x + threadIdx.x;
    if (i < n4) p[i] = make_float4(0.f, 0.f, 0.f, 0.f);
}

__global__ __launch_bounds__(256) void count_only(
    const float* __restrict__ pts, float* __restrict__ counts) {
    int idx = blockIdx.x * blockDim.x + threadIdx.x;
    if (idx >= B * N) return;
    int b = idx / N;
    const float* p = pts + (size_t)idx * 3;
    int v = voxel_of(p[0], p[1], p[2]);
    atomicAdd(counts + (size_t)b * V + v, 1.0f);
}

__global__ __launch_bounds__(256) void scatter_direct(
    const float* __restrict__ pts, const float* __restrict__ fts,
    const float* __restrict__ counts, float* __restrict__ out) {
    int idx = blockIdx.x * blockDim.x + threadIdx.x;
    if (idx >= B * N) return;
    int b = idx / N;
    const float* p = pts + (size_t)idx * 3;
    int v = voxel_of(p[0], p[1], p[2]);
    float cnt = counts[(size_t)b * V + v];
    const float* f = fts + (size_t)idx * C;
    float* o = out + (size_t)b * C * V + v;
#pragma unroll
    for (int c = 0; c < 16; ++c) atomicAdd(o + (size_t)c * V, f[c] / cnt);
}

}  // namespace

extern "C" void kernel_launch(void* const* d_in, const int* in_sizes, int n_in,
                              void* d_out, int out_size, void* d_ws, size_t ws_size,
                              hipStream_t stream) {
    const float* pts = (const float*)d_in[0];   // [B, N, 3]
    const float* fts = (const float*)d_in[1];   // [B, N, C]
    float* out = (float*)d_out;                 // [B, C, D, H, W]

    const int n_pts = B * N;                    // 400,000
    const int pt_blocks = (n_pts + 255) / 256;

    const size_t head_bytes = (size_t)BV * sizeof(unsigned);      // 16.8 MB
    const size_t nxt_bytes = (size_t)n_pts * sizeof(unsigned);    // 1.6 MB

    if (ws_size >= head_bytes + nxt_bytes) {
        unsigned* head = (unsigned*)d_ws;
        unsigned* nxt = head + (size_t)BV;

        int head_n4 = BV / 4;  // 1,048,576
        init_head<<<(head_n4 + 255) / 256, 256, 0, stream>>>((uint4*)head, head_n4);
        build_list<<<pt_blocks, 256, 0, stream>>>(pts, head, nxt);

        int fin_threads = BV / 4;  // 1,048,576 (one per 4 voxels)
        finalize<<<(fin_threads + 255) / 256, 256, 0, stream>>>(
            (const uint4*)head, nxt, (const float4*)fts, out);
    } else {
        // Safety net: direct atomic accumulation into out.
        float* counts = (float*)d_ws;
        int counts_f4 = BV / 4;
        zero_f4<<<(counts_f4 + 255) / 256, 256, 0, stream>>>((float4*)counts, counts_f4);
        int out_f4 = out_size / 4;
        zero_f4<<<(out_f4 + 255) / 256, 256, 0, stream>>>((float4*)out, out_f4);
        count_only<<<pt_blocks, 256, 0, stream>>>(pts, counts);
        scatter_direct<<<pt_blocks, 256, 0, stream>>>(pts, fts, counts, out);
    }
}